// Round 5
// baseline (1840.458 us; speedup 1.0000x reference)
//
#include <hip/hip_runtime.h>

#define F_IN  512
#define F_OUT 128
#define CB    128          // coarse bucket = 128 dst nodes
#define EPB   4096         // edges per fill block
#define NGRP  8            // sub-bins per bucket (XCD write-locality)

typedef __attribute__((ext_vector_type(8))) short  short8;
typedef __attribute__((ext_vector_type(4))) float  floatx4;

__device__ __forceinline__ unsigned short f2bf(float f) {
    unsigned u = __float_as_uint(f);
    return (unsigned short)((u + 0x7FFF + ((u >> 16) & 1)) >> 16);  // RNE
}
__device__ __forceinline__ float bf2f(unsigned b) {
    return __uint_as_float(b << 16);
}

// ---------------------------------------------------------------------------
// One-time: w fp32 [512][128] -> wt bf16 [128][512] (n-major, k-contiguous).
// ---------------------------------------------------------------------------
__global__ __launch_bounds__(256) void convert_w(
    const float* __restrict__ w, unsigned short* __restrict__ wt)
{
    int gid = blockIdx.x * 256 + threadIdx.x;      // 65536 threads
    int n = gid >> 9, k = gid & 511;
    wt[gid] = f2bf(w[(size_t)k * F_OUT + n]);
}

// ---------------------------------------------------------------------------
// GEMM: h[N,128](bf16) = x[N,512](fp32->bf16) @ w, mfma_f32_16x16x32_bf16.
// (unchanged from R4 — not the bottleneck)
// ---------------------------------------------------------------------------
__global__ __launch_bounds__(256, 2) void gemm_mfma(
    const float* __restrict__ x, const unsigned short* __restrict__ wt,
    unsigned short* __restrict__ h, int N)
{
    __shared__ unsigned short sa[64 * 68];     // [row][k]
    __shared__ unsigned short sb[128 * 68];    // [n][k]

    const int tid  = threadIdx.x;
    const int wave = tid >> 6, lane = tid & 63;
    const int g    = lane >> 4, l16 = lane & 15;
    const int m0   = blockIdx.x * 64;

    const int arow = tid >> 2, aq = tid & 3;
    const int brow = tid >> 1, bh = tid & 1;

    floatx4 acc[8];
    #pragma unroll
    for (int i = 0; i < 8; ++i) acc[i] = (floatx4)(0.f);

    const bool  avalid = (m0 + arow) < N;
    const float* xp = x + (size_t)(m0 + arow) * F_IN + aq * 16;
    const unsigned short* bp = wt + brow * F_IN + bh * 32;

    float4 ax[4];
    uint4  bv[4];
    #pragma unroll
    for (int i = 0; i < 4; ++i) ax[i] = make_float4(0.f, 0.f, 0.f, 0.f);
    if (avalid) {
        #pragma unroll
        for (int i = 0; i < 4; ++i) ax[i] = ((const float4*)xp)[i];
    }
    #pragma unroll
    for (int i = 0; i < 4; ++i) bv[i] = ((const uint4*)bp)[i];

    for (int s = 0; s < 8; ++s) {
        __syncthreads();
        #pragma unroll
        for (int i = 0; i < 4; ++i) {
            ushort4 t;
            t.x = f2bf(ax[i].x); t.y = f2bf(ax[i].y);
            t.z = f2bf(ax[i].z); t.w = f2bf(ax[i].w);
            *(ushort4*)&sa[arow * 68 + aq * 16 + i * 4] = t;
        }
        #pragma unroll
        for (int i = 0; i < 4; ++i) {
            *(uint2*)&sb[brow * 68 + bh * 32 + i * 8]     = make_uint2(bv[i].x, bv[i].y);
            *(uint2*)&sb[brow * 68 + bh * 32 + i * 8 + 4] = make_uint2(bv[i].z, bv[i].w);
        }
        if (s < 7) {
            int k0n = (s + 1) * 64;
            if (avalid) {
                #pragma unroll
                for (int i = 0; i < 4; ++i) ax[i] = ((const float4*)(xp + k0n))[i];
            }
            #pragma unroll
            for (int i = 0; i < 4; ++i) bv[i] = ((const uint4*)(bp + k0n))[i];
        }
        __syncthreads();

        #pragma unroll
        for (int kc = 0; kc < 2; ++kc) {
            union { ushort4 u[2]; short8 v; } af;
            int abase = (wave * 16 + l16) * 68 + kc * 32 + g * 8;
            af.u[0] = *(ushort4*)&sa[abase];
            af.u[1] = *(ushort4*)&sa[abase + 4];
            #pragma unroll
            for (int nt = 0; nt < 8; ++nt) {
                union { ushort4 u[2]; short8 v; } bf;
                int bbase = (nt * 16 + l16) * 68 + kc * 32 + g * 8;
                bf.u[0] = *(ushort4*)&sb[bbase];
                bf.u[1] = *(ushort4*)&sb[bbase + 4];
                acc[nt] = __builtin_amdgcn_mfma_f32_16x16x32_bf16(af.v, bf.v, acc[nt], 0, 0, 0);
            }
        }
    }

    #pragma unroll
    for (int nt = 0; nt < 8; ++nt) {
        #pragma unroll
        for (int r = 0; r < 4; ++r) {
            int row = m0 + wave * 16 + g * 4 + r;
            if (row < N) h[(size_t)row * F_OUT + nt * 16 + l16] = f2bf(acc[nt][r]);
        }
    }
}

// ---------------------------------------------------------------------------
// Coarse histogram: bin = (dst>>7)*8 + group(e), group matches fill block.
// ---------------------------------------------------------------------------
__global__ __launch_bounds__(256) void hist_coarse(
    const int* __restrict__ ei, int* __restrict__ cnt, int E)
{
    int e = blockIdx.x * 256 + threadIdx.x;
    if (e >= E) return;
    int dst = ei[E + e];
    int bin = (dst >> 7) * NGRP + ((e / EPB) & (NGRP - 1));
    atomicAdd(&cnt[bin], 1);
}

// ---------------------------------------------------------------------------
// Single-block exclusive scan of nbins (<=4096) values -> binoff & cursor.
// ---------------------------------------------------------------------------
__global__ __launch_bounds__(1024) void scan_bins(
    const int* __restrict__ cnt, int* __restrict__ binoff,
    int* __restrict__ cursor, int nbins)
{
    __shared__ int s[1024];
    int tid  = threadIdx.x;
    int base = tid * 4;
    int v[4], sum = 0;
    #pragma unroll
    for (int j = 0; j < 4; ++j) {
        int idx = base + j;
        v[j] = (idx < nbins) ? cnt[idx] : 0;
        sum += v[j];
    }
    s[tid] = sum;
    __syncthreads();
    #pragma unroll
    for (int off = 1; off < 1024; off <<= 1) {
        int t = (tid >= off) ? s[tid - off] : 0;
        __syncthreads();
        s[tid] += t;
        __syncthreads();
    }
    int ex = s[tid] - sum;
    #pragma unroll
    for (int j = 0; j < 4; ++j) {
        int idx = base + j;
        if (idx < nbins) { binoff[idx] = ex; cursor[idx] = ex; }
        ex += v[j];
    }
    if (tid == 1023) binoff[nbins] = ex;   // total == E
}

// ---------------------------------------------------------------------------
// Coarse fill: shared per-bin cursors keep the write frontier at ~3128
// cache lines (L2-resident, each line filled before eviction). Sub-binning
// by block group keeps a bin's writers on (mostly) one XCD.
// Entry: {src u16 | bf16 w << 16, dst & 127}.
// ---------------------------------------------------------------------------
__global__ __launch_bounds__(256) void fill_coarse(
    const int* __restrict__ ei, const float* __restrict__ ew,
    int* __restrict__ cursor, uint2* __restrict__ bucket, int E)
{
    int base = blockIdx.x * EPB;
    int grp  = blockIdx.x & (NGRP - 1);
    #pragma unroll 1
    for (int k = 0; k < EPB / 256; ++k) {
        int e = base + k * 256 + threadIdx.x;
        if (e >= E) return;
        int   src = ei[e];
        int   dst = ei[E + e];
        float w   = ew[e];
        int bin = (dst >> 7) * NGRP + grp;
        int pos = atomicAdd(&cursor[bin], 1);
        bucket[pos] = make_uint2((unsigned)src | ((unsigned)f2bf(w) << 16),
                                 (unsigned)(dst & (CB - 1)));
    }
}

// ---------------------------------------------------------------------------
// Aggregate: one block per coarse bucket. 128x128 fp32 accumulator in LDS
// (64 KB, 2 blocks/CU). Lane l owns feats {l, l+64}: gathers are two 128 B
// coalesced ushort loads; ds_add_f32 banks are 2-way (free). Fused
// bias+relu writeout, out written exactly once.
// ---------------------------------------------------------------------------
__global__ __launch_bounds__(256, 2) void aggregate_lds(
    const unsigned short* __restrict__ h, const uint2* __restrict__ bucket,
    const int* __restrict__ binoff, const float* __restrict__ bias,
    float* __restrict__ out, int N)
{
    __shared__ float acc[CB * F_OUT];          // 64 KB

    const int b    = blockIdx.x;
    const int tid  = threadIdx.x;
    const int wave = tid >> 6, lane = tid & 63;

    #pragma unroll
    for (int i = 0; i < (CB * F_OUT) / 256; ++i) acc[tid + i * 256] = 0.f;
    __syncthreads();

    const int start = binoff[b * NGRP];
    const int end   = binoff[b * NGRP + NGRP];
    const int cntE  = end - start;
    const int per   = (cntE + 3) >> 2;
    const int ws    = start + wave * per;
    const int we    = min(ws + per, end);

    int i = ws;
    for (; i + 4 <= we; i += 4) {
        uint2 e0 = bucket[i], e1 = bucket[i + 1], e2 = bucket[i + 2], e3 = bucket[i + 3];
        int s0 = e0.x & 0xFFFF, s1 = e1.x & 0xFFFF, s2 = e2.x & 0xFFFF, s3 = e3.x & 0xFFFF;
        unsigned short a0 = h[s0 * F_OUT + lane],      c0 = h[s0 * F_OUT + 64 + lane];
        unsigned short a1 = h[s1 * F_OUT + lane],      c1 = h[s1 * F_OUT + 64 + lane];
        unsigned short a2 = h[s2 * F_OUT + lane],      c2 = h[s2 * F_OUT + 64 + lane];
        unsigned short a3 = h[s3 * F_OUT + lane],      c3 = h[s3 * F_OUT + 64 + lane];
        float w0 = bf2f(e0.x >> 16), w1 = bf2f(e1.x >> 16);
        float w2 = bf2f(e2.x >> 16), w3 = bf2f(e3.x >> 16);
        atomicAdd(&acc[e0.y * F_OUT + lane],      bf2f(a0) * w0);
        atomicAdd(&acc[e0.y * F_OUT + 64 + lane], bf2f(c0) * w0);
        atomicAdd(&acc[e1.y * F_OUT + lane],      bf2f(a1) * w1);
        atomicAdd(&acc[e1.y * F_OUT + 64 + lane], bf2f(c1) * w1);
        atomicAdd(&acc[e2.y * F_OUT + lane],      bf2f(a2) * w2);
        atomicAdd(&acc[e2.y * F_OUT + 64 + lane], bf2f(c2) * w2);
        atomicAdd(&acc[e3.y * F_OUT + lane],      bf2f(a3) * w3);
        atomicAdd(&acc[e3.y * F_OUT + 64 + lane], bf2f(c3) * w3);
    }
    for (; i < we; ++i) {
        uint2 e = bucket[i];
        int s = e.x & 0xFFFF;
        unsigned short a = h[s * F_OUT + lane], c = h[s * F_OUT + 64 + lane];
        float w = bf2f(e.x >> 16);
        atomicAdd(&acc[e.y * F_OUT + lane],      bf2f(a) * w);
        atomicAdd(&acc[e.y * F_OUT + 64 + lane], bf2f(c) * w);
    }
    __syncthreads();

    const int node0 = b * CB;
    #pragma unroll
    for (int j = 0; j < (CB * F_OUT) / 256; ++j) {
        int idx  = tid + j * 256;
        int node = node0 + (idx >> 7);
        if (node < N) {
            float v = acc[idx] + bias[idx & (F_OUT - 1)];
            out[(size_t)node * F_OUT + (idx & (F_OUT - 1))] = fmaxf(v, 0.f);
        }
    }
}

static inline size_t align256(size_t x) { return (x + 255) & ~(size_t)255; }

extern "C" void kernel_launch(void* const* d_in, const int* in_sizes, int n_in,
                              void* d_out, int out_size, void* d_ws, size_t ws_size,
                              hipStream_t stream)
{
    const float* x    = (const float*)d_in[0];   // [N, 512]
    const int*   ei   = (const int*)  d_in[1];   // [2, E] int32
    const float* ew   = (const float*)d_in[2];   // [E]
    const float* w    = (const float*)d_in[3];   // [512, 128]
    const float* bias = (const float*)d_in[4];   // [128]
    float*       out  = (float*)d_out;           // [N, 128]

    const int N = in_sizes[0] / F_IN;            // 50000
    const int E = in_sizes[2];                   // 1600000

    const int C     = (N + CB - 1) / CB;         // 391 coarse buckets
    const int nbins = C * NGRP;                  // 3128

    // workspace layout (~26 MB)
    char*  ws = (char*)d_ws;
    size_t off = 0;
    unsigned short* h      = (unsigned short*)(ws + off); off += align256((size_t)N * F_OUT * 2);
    unsigned short* wt     = (unsigned short*)(ws + off); off += align256((size_t)F_OUT * F_IN * 2);
    int*            cnt    = (int*)(ws + off);            off += align256((size_t)nbins * 4);
    int*            binoff = (int*)(ws + off);            off += align256((size_t)(nbins + 1) * 4);
    int*            cursor = (int*)(ws + off);            off += align256((size_t)nbins * 4);
    uint2*          bucket = (uint2*)(ws + off);          off += align256((size_t)E * 8);

    // coarse partition
    (void)hipMemsetAsync(cnt, 0, (size_t)nbins * 4, stream);
    hist_coarse<<<(E + 255) / 256, 256, 0, stream>>>(ei, cnt, E);
    scan_bins<<<1, 1024, 0, stream>>>(cnt, binoff, cursor, nbins);
    fill_coarse<<<(E + EPB - 1) / EPB, 256, 0, stream>>>(ei, ew, cursor, bucket, E);

    // dense transform (bf16 MFMA)
    convert_w<<<(F_IN * F_OUT) / 256, 256, 0, stream>>>(w, wt);
    gemm_mfma<<<(N + 63) / 64, 256, 0, stream>>>(x, wt, h, N);

    // aggregate + fused epilogue
    aggregate_lds<<<C, 256, 0, stream>>>(h, bucket, binoff, bias, out, N);
}

// Round 6
// 298.994 us; speedup vs baseline: 6.1555x; 6.1555x over previous
//
#include <hip/hip_runtime.h>

#define F_IN  512
#define F_OUT 128
#define CB    128          // nodes per coarse bucket
#define EPB   4096         // edges per partition block
#define CMAX  512          // max coarse buckets (N <= 65536)

typedef __attribute__((ext_vector_type(8))) short  short8;
typedef __attribute__((ext_vector_type(4))) float  floatx4;

__device__ __forceinline__ unsigned short f2bf(float f) {
    unsigned u = __float_as_uint(f);
    return (unsigned short)((u + 0x7FFF + ((u >> 16) & 1)) >> 16);  // RNE
}
__device__ __forceinline__ float bf2f(unsigned b) {
    return __uint_as_float(b << 16);
}

// ---------------------------------------------------------------------------
// One-time: w fp32 [512][128] -> wt bf16 [128][512] (n-major, k-contiguous).
// ---------------------------------------------------------------------------
__global__ __launch_bounds__(256) void convert_w(
    const float* __restrict__ w, unsigned short* __restrict__ wt)
{
    int gid = blockIdx.x * 256 + threadIdx.x;      // 65536 threads
    int n = gid >> 9, k = gid & 511;
    wt[gid] = f2bf(w[(size_t)k * F_OUT + n]);
}

// ---------------------------------------------------------------------------
// GEMM: h[N,128](bf16) = x[N,512](fp32->bf16) @ w, mfma_f32_16x16x32_bf16.
// (unchanged from R4 — not the bottleneck)
// ---------------------------------------------------------------------------
__global__ __launch_bounds__(256, 2) void gemm_mfma(
    const float* __restrict__ x, const unsigned short* __restrict__ wt,
    unsigned short* __restrict__ h, int N)
{
    __shared__ unsigned short sa[64 * 68];     // [row][k]
    __shared__ unsigned short sb[128 * 68];    // [n][k]

    const int tid  = threadIdx.x;
    const int wave = tid >> 6, lane = tid & 63;
    const int g    = lane >> 4, l16 = lane & 15;
    const int m0   = blockIdx.x * 64;

    const int arow = tid >> 2, aq = tid & 3;
    const int brow = tid >> 1, bh = tid & 1;

    floatx4 acc[8];
    #pragma unroll
    for (int i = 0; i < 8; ++i) acc[i] = (floatx4)(0.f);

    const bool  avalid = (m0 + arow) < N;
    const float* xp = x + (size_t)(m0 + arow) * F_IN + aq * 16;
    const unsigned short* bp = wt + brow * F_IN + bh * 32;

    float4 ax[4];
    uint4  bv[4];
    #pragma unroll
    for (int i = 0; i < 4; ++i) ax[i] = make_float4(0.f, 0.f, 0.f, 0.f);
    if (avalid) {
        #pragma unroll
        for (int i = 0; i < 4; ++i) ax[i] = ((const float4*)xp)[i];
    }
    #pragma unroll
    for (int i = 0; i < 4; ++i) bv[i] = ((const uint4*)bp)[i];

    for (int s = 0; s < 8; ++s) {
        __syncthreads();
        #pragma unroll
        for (int i = 0; i < 4; ++i) {
            ushort4 t;
            t.x = f2bf(ax[i].x); t.y = f2bf(ax[i].y);
            t.z = f2bf(ax[i].z); t.w = f2bf(ax[i].w);
            *(ushort4*)&sa[arow * 68 + aq * 16 + i * 4] = t;
        }
        #pragma unroll
        for (int i = 0; i < 4; ++i) {
            *(uint2*)&sb[brow * 68 + bh * 32 + i * 8]     = make_uint2(bv[i].x, bv[i].y);
            *(uint2*)&sb[brow * 68 + bh * 32 + i * 8 + 4] = make_uint2(bv[i].z, bv[i].w);
        }
        if (s < 7) {
            int k0n = (s + 1) * 64;
            if (avalid) {
                #pragma unroll
                for (int i = 0; i < 4; ++i) ax[i] = ((const float4*)(xp + k0n))[i];
            }
            #pragma unroll
            for (int i = 0; i < 4; ++i) bv[i] = ((const uint4*)(bp + k0n))[i];
        }
        __syncthreads();

        #pragma unroll
        for (int kc = 0; kc < 2; ++kc) {
            union { ushort4 u[2]; short8 v; } af;
            int abase = (wave * 16 + l16) * 68 + kc * 32 + g * 8;
            af.u[0] = *(ushort4*)&sa[abase];
            af.u[1] = *(ushort4*)&sa[abase + 4];
            #pragma unroll
            for (int nt = 0; nt < 8; ++nt) {
                union { ushort4 u[2]; short8 v; } bf;
                int bbase = (nt * 16 + l16) * 68 + kc * 32 + g * 8;
                bf.u[0] = *(ushort4*)&sb[bbase];
                bf.u[1] = *(ushort4*)&sb[bbase + 4];
                acc[nt] = __builtin_amdgcn_mfma_f32_16x16x32_bf16(af.v, bf.v, acc[nt], 0, 0, 0);
            }
        }
    }

    #pragma unroll
    for (int nt = 0; nt < 8; ++nt) {
        #pragma unroll
        for (int r = 0; r < 4; ++r) {
            int row = m0 + wave * 16 + g * 4 + r;
            if (row < N) h[(size_t)row * F_OUT + nt * 16 + l16] = f2bf(acc[nt][r]);
        }
    }
}

// ---------------------------------------------------------------------------
// Partition 1: coarse histogram (bin = dst >> 7), LDS-aggregated.
// ---------------------------------------------------------------------------
__global__ __launch_bounds__(512) void coarse_hist(
    const int* __restrict__ ei, int* __restrict__ cnt, int E, int C)
{
    __shared__ int lh[CMAX];
    int tid = threadIdx.x;
    if (tid < CMAX) lh[tid] = 0;
    __syncthreads();
    int base = blockIdx.x * EPB;
    #pragma unroll
    for (int j = 0; j < EPB / 512; ++j) {
        int e = base + j * 512 + tid;
        if (e < E) atomicAdd(&lh[ei[E + e] >> 7], 1);
    }
    __syncthreads();
    if (tid < C && lh[tid] > 0) atomicAdd(&cnt[tid], lh[tid]);
}

// ---------------------------------------------------------------------------
// Partition 2: single-block exclusive scan of C (<=512) bins.
// Also seeds cursor, binoff[C]=E, rowptr[N]=E.
// ---------------------------------------------------------------------------
__global__ __launch_bounds__(512) void scan_coarse(
    const int* __restrict__ cnt, int* __restrict__ binoff,
    int* __restrict__ cursor, int* __restrict__ rowptr, int C, int N, int E)
{
    __shared__ int s[CMAX];
    int tid = threadIdx.x;
    int v = (tid < C) ? cnt[tid] : 0;
    s[tid] = v;
    __syncthreads();
    #pragma unroll
    for (int off = 1; off < CMAX; off <<= 1) {
        int t = (tid >= off) ? s[tid - off] : 0;
        __syncthreads();
        s[tid] += t;
        __syncthreads();
    }
    if (tid < C) { int ex = s[tid] - v; binoff[tid] = ex; cursor[tid] = ex; }
    if (tid == 0) { binoff[C] = E; rowptr[N] = E; }
}

// ---------------------------------------------------------------------------
// Partition 3: coarse fill. Per block: LDS rank per edge + ONE batched
// cursor claim per bin -> each block writes ~10-entry contiguous runs
// (line-local, single-XCD). Outputs: k32 = {src u16 | bf16 w}, d8 = dst&127.
// ---------------------------------------------------------------------------
__global__ __launch_bounds__(512) void coarse_fill(
    const int* __restrict__ ei, const float* __restrict__ ew,
    int* __restrict__ cursor, unsigned* __restrict__ k32,
    unsigned char* __restrict__ d8, int E, int C)
{
    __shared__ int lh[CMAX];
    __shared__ int lbase[CMAX];
    int tid = threadIdx.x;
    if (tid < CMAX) lh[tid] = 0;
    __syncthreads();

    const int base = blockIdx.x * EPB;
    unsigned      mykey[EPB / 512];
    unsigned char mydl[EPB / 512];
    short         mybin[EPB / 512];
    unsigned short myrank[EPB / 512];

    #pragma unroll
    for (int j = 0; j < EPB / 512; ++j) {
        int e = base + j * 512 + tid;
        mybin[j] = -1;
        if (e < E) {
            int   src = ei[e];
            int   dst = ei[E + e];
            float w   = ew[e];
            int bin = dst >> 7;
            mykey[j]  = (unsigned)src | ((unsigned)f2bf(w) << 16);
            mydl[j]   = (unsigned char)(dst & (CB - 1));
            mybin[j]  = (short)bin;
            myrank[j] = (unsigned short)atomicAdd(&lh[bin], 1);
        }
    }
    __syncthreads();
    if (tid < C && lh[tid] > 0) lbase[tid] = atomicAdd(&cursor[tid], lh[tid]);
    __syncthreads();
    #pragma unroll
    for (int j = 0; j < EPB / 512; ++j) {
        if (mybin[j] >= 0) {
            int p = lbase[mybin[j]] + myrank[j];
            k32[p] = mykey[j];
            d8[p]  = mydl[j];
        }
    }
}

// ---------------------------------------------------------------------------
// Partition 4: fine fill. One block per coarse bucket: LDS 128-node hist +
// scan + scatter into the bucket's contiguous region. Writes rowptr directly.
// ---------------------------------------------------------------------------
__global__ __launch_bounds__(512) void fine_fill(
    const unsigned* __restrict__ k32, const unsigned char* __restrict__ d8,
    const int* __restrict__ binoff, unsigned* __restrict__ bucket,
    int* __restrict__ rowptr, int N)
{
    __shared__ int lh[CB];
    __shared__ int ss[CB];
    __shared__ int lcur[CB];

    const int b   = blockIdx.x;
    const int tid = threadIdx.x;
    const int start = binoff[b];
    const int end   = binoff[b + 1];

    if (tid < CB) lh[tid] = 0;
    __syncthreads();
    for (int i = start + tid; i < end; i += 512)
        atomicAdd(&lh[d8[i]], 1);
    __syncthreads();

    // exclusive scan of 128 counts (block-wide barriers, first 128 lanes active)
    if (tid < CB) ss[tid] = lh[tid];
    __syncthreads();
    #pragma unroll
    for (int off = 1; off < CB; off <<= 1) {
        int t = 0;
        if (tid < CB && tid >= off) t = ss[tid - off];
        __syncthreads();
        if (tid < CB) ss[tid] += t;
        __syncthreads();
    }
    if (tid < CB) {
        int ex = ss[tid] - lh[tid];
        lcur[tid] = ex;
        int node = b * CB + tid;
        if (node < N) rowptr[node] = start + ex;
    }
    __syncthreads();

    for (int i = start + tid; i < end; i += 512) {
        int nd = d8[i];
        int r  = atomicAdd(&lcur[nd], 1);
        bucket[start + r] = k32[i];
    }
}

// ---------------------------------------------------------------------------
// Aggregate: one wave per node, lane = 2 features (bf16 h, fp32 acc).
// Fused bias + relu; out written exactly once. (R4 version — proven.)
// ---------------------------------------------------------------------------
__global__ __launch_bounds__(256) void aggregate_csr(
    const unsigned short* __restrict__ h, const unsigned* __restrict__ bucket,
    const int* __restrict__ rowptr, const float* __restrict__ bias,
    float* __restrict__ out, int N)
{
    int wave = threadIdx.x >> 6;
    int lane = threadIdx.x & 63;
    int n    = blockIdx.x * 4 + wave;
    if (n >= N) return;

    int start = rowptr[n];
    int end   = rowptr[n + 1];

    float accx = 0.f, accy = 0.f;
    int i = start;
    for (; i + 4 <= end; i += 4) {
        unsigned b0 = bucket[i], b1 = bucket[i + 1], b2 = bucket[i + 2], b3 = bucket[i + 3];
        unsigned h0 = *(const unsigned*)&h[(size_t)(b0 & 0xFFFF) * F_OUT + lane * 2];
        unsigned h1 = *(const unsigned*)&h[(size_t)(b1 & 0xFFFF) * F_OUT + lane * 2];
        unsigned h2 = *(const unsigned*)&h[(size_t)(b2 & 0xFFFF) * F_OUT + lane * 2];
        unsigned h3 = *(const unsigned*)&h[(size_t)(b3 & 0xFFFF) * F_OUT + lane * 2];
        float w0 = bf2f(b0 >> 16), w1 = bf2f(b1 >> 16);
        float w2 = bf2f(b2 >> 16), w3 = bf2f(b3 >> 16);
        accx += bf2f(h0 & 0xFFFF) * w0; accy += bf2f(h0 >> 16) * w0;
        accx += bf2f(h1 & 0xFFFF) * w1; accy += bf2f(h1 >> 16) * w1;
        accx += bf2f(h2 & 0xFFFF) * w2; accy += bf2f(h2 >> 16) * w2;
        accx += bf2f(h3 & 0xFFFF) * w3; accy += bf2f(h3 >> 16) * w3;
    }
    for (; i < end; ++i) {
        unsigned b  = bucket[i];
        unsigned hv = *(const unsigned*)&h[(size_t)(b & 0xFFFF) * F_OUT + lane * 2];
        float wgt = bf2f(b >> 16);
        accx += bf2f(hv & 0xFFFF) * wgt;
        accy += bf2f(hv >> 16) * wgt;
    }

    float2 bv = *(const float2*)&bias[lane * 2];
    float2 o;
    o.x = fmaxf(accx + bv.x, 0.f);
    o.y = fmaxf(accy + bv.y, 0.f);
    *(float2*)&out[(size_t)n * F_OUT + lane * 2] = o;
}

static inline size_t align256(size_t x) { return (x + 255) & ~(size_t)255; }

extern "C" void kernel_launch(void* const* d_in, const int* in_sizes, int n_in,
                              void* d_out, int out_size, void* d_ws, size_t ws_size,
                              hipStream_t stream)
{
    const float* x    = (const float*)d_in[0];   // [N, 512]
    const int*   ei   = (const int*)  d_in[1];   // [2, E] int32
    const float* ew   = (const float*)d_in[2];   // [E]
    const float* w    = (const float*)d_in[3];   // [512, 128]
    const float* bias = (const float*)d_in[4];   // [128]
    float*       out  = (float*)d_out;           // [N, 128]

    const int N = in_sizes[0] / F_IN;            // 50000
    const int E = in_sizes[2];                   // 1600000
    const int C = (N + CB - 1) / CB;             // 391 coarse buckets

    // workspace layout (~27.5 MB)
    char*  ws = (char*)d_ws;
    size_t off = 0;
    unsigned short* h      = (unsigned short*)(ws + off); off += align256((size_t)N * F_OUT * 2);
    unsigned short* wt     = (unsigned short*)(ws + off); off += align256((size_t)F_OUT * F_IN * 2);
    int*            cnt    = (int*)(ws + off);            off += align256((size_t)(C + 1) * 4);
    int*            binoff = (int*)(ws + off);            off += align256((size_t)(C + 1) * 4);
    int*            cursor = (int*)(ws + off);            off += align256((size_t)C * 4);
    int*            rowptr = (int*)(ws + off);            off += align256((size_t)(N + 1) * 4);
    unsigned*       k32    = (unsigned*)(ws + off);       off += align256((size_t)E * 4);
    unsigned char*  d8     = (unsigned char*)(ws + off);  off += align256((size_t)E);
    unsigned*       bucket = (unsigned*)(ws + off);       off += align256((size_t)E * 4);

    const int pblocks = (E + EPB - 1) / EPB;     // 391

    // hierarchical partition
    (void)hipMemsetAsync(cnt, 0, (size_t)C * 4, stream);
    coarse_hist<<<pblocks, 512, 0, stream>>>(ei, cnt, E, C);
    scan_coarse<<<1, 512, 0, stream>>>(cnt, binoff, cursor, rowptr, C, N, E);
    coarse_fill<<<pblocks, 512, 0, stream>>>(ei, ew, cursor, k32, d8, E, C);
    fine_fill<<<C, 512, 0, stream>>>(k32, d8, binoff, bucket, rowptr, N);

    // dense transform (bf16 MFMA)
    convert_w<<<(F_IN * F_OUT) / 256, 256, 0, stream>>>(w, wt);
    gemm_mfma<<<(N + 63) / 64, 256, 0, stream>>>(x, wt, h, N);

    // aggregate + fused epilogue
    aggregate_csr<<<(N + 3) / 4, 256, 0, stream>>>(h, bucket, rowptr, bias, out, N);
}

// Round 7
// 280.949 us; speedup vs baseline: 6.5509x; 1.0642x over previous
//
#include <hip/hip_runtime.h>

#define F_IN  512
#define F_OUT 128
#define CB    128          // nodes per coarse bucket
#define EPB   4096         // edges per partition block
#define CMAX  512          // max coarse buckets (N <= 65536)
#define CAP   8192         // max edges per bucket handled in LDS (mean 4096)

typedef __attribute__((ext_vector_type(8))) short  short8;
typedef __attribute__((ext_vector_type(4))) float  floatx4;

__device__ __forceinline__ unsigned short f2bf(float f) {
    unsigned u = __float_as_uint(f);
    return (unsigned short)((u + 0x7FFF + ((u >> 16) & 1)) >> 16);  // RNE
}
__device__ __forceinline__ float bf2f(unsigned b) {
    return __uint_as_float(b << 16);
}

// ---------------------------------------------------------------------------
// GEMM: h[N,128](bf16) = x[N,512](fp32->bf16) @ w, mfma_f32_16x16x32_bf16.
// (unchanged from R6 — attack next round if it surfaces in top-5)
// ---------------------------------------------------------------------------
__global__ __launch_bounds__(256, 2) void gemm_mfma(
    const float* __restrict__ x, const unsigned short* __restrict__ wt,
    unsigned short* __restrict__ h, int N)
{
    __shared__ unsigned short sa[64 * 68];     // [row][k]
    __shared__ unsigned short sb[128 * 68];    // [n][k]

    const int tid  = threadIdx.x;
    const int wave = tid >> 6, lane = tid & 63;
    const int g    = lane >> 4, l16 = lane & 15;
    const int m0   = blockIdx.x * 64;

    const int arow = tid >> 2, aq = tid & 3;
    const int brow = tid >> 1, bh = tid & 1;

    floatx4 acc[8];
    #pragma unroll
    for (int i = 0; i < 8; ++i) acc[i] = (floatx4)(0.f);

    const bool  avalid = (m0 + arow) < N;
    const float* xp = x + (size_t)(m0 + arow) * F_IN + aq * 16;
    const unsigned short* bp = wt + brow * F_IN + bh * 32;

    float4 ax[4];
    uint4  bv[4];
    #pragma unroll
    for (int i = 0; i < 4; ++i) ax[i] = make_float4(0.f, 0.f, 0.f, 0.f);
    if (avalid) {
        #pragma unroll
        for (int i = 0; i < 4; ++i) ax[i] = ((const float4*)xp)[i];
    }
    #pragma unroll
    for (int i = 0; i < 4; ++i) bv[i] = ((const uint4*)bp)[i];

    for (int s = 0; s < 8; ++s) {
        __syncthreads();
        #pragma unroll
        for (int i = 0; i < 4; ++i) {
            ushort4 t;
            t.x = f2bf(ax[i].x); t.y = f2bf(ax[i].y);
            t.z = f2bf(ax[i].z); t.w = f2bf(ax[i].w);
            *(ushort4*)&sa[arow * 68 + aq * 16 + i * 4] = t;
        }
        #pragma unroll
        for (int i = 0; i < 4; ++i) {
            *(uint2*)&sb[brow * 68 + bh * 32 + i * 8]     = make_uint2(bv[i].x, bv[i].y);
            *(uint2*)&sb[brow * 68 + bh * 32 + i * 8 + 4] = make_uint2(bv[i].z, bv[i].w);
        }
        if (s < 7) {
            int k0n = (s + 1) * 64;
            if (avalid) {
                #pragma unroll
                for (int i = 0; i < 4; ++i) ax[i] = ((const float4*)(xp + k0n))[i];
            }
            #pragma unroll
            for (int i = 0; i < 4; ++i) bv[i] = ((const uint4*)(bp + k0n))[i];
        }
        __syncthreads();

        #pragma unroll
        for (int kc = 0; kc < 2; ++kc) {
            union { ushort4 u[2]; short8 v; } af;
            int abase = (wave * 16 + l16) * 68 + kc * 32 + g * 8;
            af.u[0] = *(ushort4*)&sa[abase];
            af.u[1] = *(ushort4*)&sa[abase + 4];
            #pragma unroll
            for (int nt = 0; nt < 8; ++nt) {
                union { ushort4 u[2]; short8 v; } bf;
                int bbase = (nt * 16 + l16) * 68 + kc * 32 + g * 8;
                bf.u[0] = *(ushort4*)&sb[bbase];
                bf.u[1] = *(ushort4*)&sb[bbase + 4];
                acc[nt] = __builtin_amdgcn_mfma_f32_16x16x32_bf16(af.v, bf.v, acc[nt], 0, 0, 0);
            }
        }
    }

    #pragma unroll
    for (int nt = 0; nt < 8; ++nt) {
        #pragma unroll
        for (int r = 0; r < 4; ++r) {
            int row = m0 + wave * 16 + g * 4 + r;
            if (row < N) h[(size_t)row * F_OUT + nt * 16 + l16] = f2bf(acc[nt][r]);
        }
    }
}

// ---------------------------------------------------------------------------
// Partition 1: coarse histogram (bin = dst >> 7), LDS-aggregated.
// ---------------------------------------------------------------------------
__global__ __launch_bounds__(512) void coarse_hist(
    const int* __restrict__ ei, int* __restrict__ cnt, int E, int C)
{
    __shared__ int lh[CMAX];
    int tid = threadIdx.x;
    if (tid < CMAX) lh[tid] = 0;
    __syncthreads();
    int base = blockIdx.x * EPB;
    #pragma unroll
    for (int j = 0; j < EPB / 512; ++j) {
        int e = base + j * 512 + tid;
        if (e < E) atomicAdd(&lh[ei[E + e] >> 7], 1);
    }
    __syncthreads();
    if (tid < C && lh[tid] > 0) atomicAdd(&cnt[tid], lh[tid]);
}

// ---------------------------------------------------------------------------
// Partition 2 + w convert, fused in one launch (grid = 1 + 128):
//   block 0      : exclusive scan of C (<=512) coarse bins -> binoff, cursor
//   blocks 1..128: w fp32 [512][128] -> wt bf16 [128][512]
// ---------------------------------------------------------------------------
__global__ __launch_bounds__(512) void scan_convert(
    const int* __restrict__ cnt, int* __restrict__ binoff,
    int* __restrict__ cursor, int C, int E,
    const float* __restrict__ w, unsigned short* __restrict__ wt)
{
    if (blockIdx.x > 0) {
        int gid = (blockIdx.x - 1) * 512 + threadIdx.x;   // 128*512 = 65536
        int n = gid >> 9, k = gid & 511;
        wt[gid] = f2bf(w[(size_t)k * F_OUT + n]);
        return;
    }
    __shared__ int s[CMAX];
    int tid = threadIdx.x;
    int v = (tid < C) ? cnt[tid] : 0;
    s[tid] = v;
    __syncthreads();
    #pragma unroll
    for (int off = 1; off < CMAX; off <<= 1) {
        int t = (tid >= off) ? s[tid - off] : 0;
        __syncthreads();
        s[tid] += t;
        __syncthreads();
    }
    if (tid < C) { int ex = s[tid] - v; binoff[tid] = ex; cursor[tid] = ex; }
    if (tid == 0) binoff[C] = E;
}

// ---------------------------------------------------------------------------
// Partition 3: coarse fill. Per block: LDS rank per edge + ONE batched
// cursor claim per bin -> ~10-entry contiguous runs (line-local).
// Outputs: k32 = {src u16 | bf16 w}, d8 = dst & 127.
// ---------------------------------------------------------------------------
__global__ __launch_bounds__(512) void coarse_fill(
    const int* __restrict__ ei, const float* __restrict__ ew,
    int* __restrict__ cursor, unsigned* __restrict__ k32,
    unsigned char* __restrict__ d8, int E, int C)
{
    __shared__ int lh[CMAX];
    __shared__ int lbase[CMAX];
    int tid = threadIdx.x;
    if (tid < CMAX) lh[tid] = 0;
    __syncthreads();

    const int base = blockIdx.x * EPB;
    unsigned       mykey[EPB / 512];
    unsigned char  mydl[EPB / 512];
    short          mybin[EPB / 512];
    unsigned short myrank[EPB / 512];

    #pragma unroll
    for (int j = 0; j < EPB / 512; ++j) {
        int e = base + j * 512 + tid;
        mybin[j] = -1;
        if (e < E) {
            int   src = ei[e];
            int   dst = ei[E + e];
            float w   = ew[e];
            int bin = dst >> 7;
            mykey[j]  = (unsigned)src | ((unsigned)f2bf(w) << 16);
            mydl[j]   = (unsigned char)(dst & (CB - 1));
            mybin[j]  = (short)bin;
            myrank[j] = (unsigned short)atomicAdd(&lh[bin], 1);
        }
    }
    __syncthreads();
    if (tid < C && lh[tid] > 0) lbase[tid] = atomicAdd(&cursor[tid], lh[tid]);
    __syncthreads();
    #pragma unroll
    for (int j = 0; j < EPB / 512; ++j) {
        if (mybin[j] >= 0) {
            int p = lbase[mybin[j]] + myrank[j];
            k32[p] = mykey[j];
            d8[p]  = mydl[j];
        }
    }
}

// ---------------------------------------------------------------------------
// Fused fine-sort + aggregate: one block per coarse bucket.
//   Phase A: d8 -> LDS, 128-node hist + scan, scatter k32 into sorted LDS.
//   Phase B: wave per 16 nodes; lanes split 32/32 over even/odd edges;
//            lane covers 4 feats via one uint2 gather (half-wave = full row);
//            shfl_xor(32) reduce; half-wave float4 writeout w/ bias+relu.
// ---------------------------------------------------------------------------
__global__ __launch_bounds__(512) void fine_agg(
    const unsigned short* __restrict__ h, const unsigned* __restrict__ k32,
    const unsigned char* __restrict__ d8, const int* __restrict__ binoff,
    const float* __restrict__ bias, float* __restrict__ out, int N)
{
    __shared__ unsigned char sd[CAP];        //  8 KB
    __shared__ unsigned      ssort[CAP];     // 32 KB
    __shared__ int lh[CB], ssum[CB], lcur[CB];
    __shared__ int sso[CB + 1];

    const int b     = blockIdx.x;
    const int tid   = threadIdx.x;
    const int start = binoff[b];
    const int cnt   = binoff[b + 1] - start;
    const int wave  = tid >> 6;
    const int lane  = tid & 63;
    const int half  = lane >> 5;             // 0: even edges, 1: odd edges
    const int q     = lane & 31;             // feature group: feats q*4..q*4+3
    const float4 bv = *(const float4*)&bias[q * 4];

    if (cnt <= CAP) {
        if (tid < CB) lh[tid] = 0;
        __syncthreads();
        for (int i = tid; i < cnt; i += 512) {
            unsigned char d = d8[start + i];
            sd[i] = d;
            atomicAdd(&lh[d], 1);
        }
        __syncthreads();
        if (tid < CB) ssum[tid] = lh[tid];
        __syncthreads();
        #pragma unroll
        for (int off = 1; off < CB; off <<= 1) {
            int t = 0;
            if (tid < CB && tid >= off) t = ssum[tid - off];
            __syncthreads();
            if (tid < CB) ssum[tid] += t;
            __syncthreads();
        }
        if (tid < CB) {
            int ex = ssum[tid] - lh[tid];
            sso[tid]  = ex;
            lcur[tid] = ex;
        }
        if (tid == 0) sso[CB] = cnt;
        __syncthreads();
        for (int i = tid; i < cnt; i += 512) {
            unsigned k = k32[start + i];
            int r = atomicAdd(&lcur[sd[i]], 1);
            ssort[r] = k;
        }
        __syncthreads();

        #pragma unroll 1
        for (int t = 0; t < 16; ++t) {
            int nd   = wave * 16 + t;
            int node = b * CB + nd;
            int s    = sso[nd], e = sso[nd + 1];
            float4 acc = make_float4(0.f, 0.f, 0.f, 0.f);
            for (int i = s; i < e; i += 8) {
                #pragma unroll
                for (int j = 0; j < 4; ++j) {
                    int idx = i + j * 2 + half;
                    unsigned bk = 0;
                    if (idx < e) bk = ssort[idx];
                    float wgt = bf2f(bk >> 16);
                    uint2 hv = *(const uint2*)&h[(size_t)(bk & 0xFFFF) * F_OUT + q * 4];
                    acc.x += bf2f(hv.x & 0xFFFF) * wgt;
                    acc.y += bf2f(hv.x >> 16)    * wgt;
                    acc.z += bf2f(hv.y & 0xFFFF) * wgt;
                    acc.w += bf2f(hv.y >> 16)    * wgt;
                }
            }
            acc.x += __shfl_xor(acc.x, 32);
            acc.y += __shfl_xor(acc.y, 32);
            acc.z += __shfl_xor(acc.z, 32);
            acc.w += __shfl_xor(acc.w, 32);
            if (half == 0 && node < N) {
                float4 o;
                o.x = fmaxf(acc.x + bv.x, 0.f);
                o.y = fmaxf(acc.y + bv.y, 0.f);
                o.z = fmaxf(acc.z + bv.z, 0.f);
                o.w = fmaxf(acc.w + bv.w, 0.f);
                *(float4*)&out[(size_t)node * F_OUT + q * 4] = o;
            }
        }
    } else {
        // pathological bucket (> CAP edges): correct-but-slow global scan
        #pragma unroll 1
        for (int t = 0; t < 16; ++t) {
            int nd   = wave * 16 + t;
            int node = b * CB + nd;
            float4 acc = make_float4(0.f, 0.f, 0.f, 0.f);
            for (int i = 0; i < cnt; ++i) {
                if (d8[start + i] == (unsigned char)nd) {
                    unsigned bk = k32[start + i];
                    float wgt = bf2f(bk >> 16);
                    uint2 hv = *(const uint2*)&h[(size_t)(bk & 0xFFFF) * F_OUT + q * 4];
                    acc.x += bf2f(hv.x & 0xFFFF) * wgt;
                    acc.y += bf2f(hv.x >> 16)    * wgt;
                    acc.z += bf2f(hv.y & 0xFFFF) * wgt;
                    acc.w += bf2f(hv.y >> 16)    * wgt;
                }
            }
            if (half == 0 && node < N) {
                float4 o;
                o.x = fmaxf(acc.x + bv.x, 0.f);
                o.y = fmaxf(acc.y + bv.y, 0.f);
                o.z = fmaxf(acc.z + bv.z, 0.f);
                o.w = fmaxf(acc.w + bv.w, 0.f);
                *(float4*)&out[(size_t)node * F_OUT + q * 4] = o;
            }
        }
    }
}

static inline size_t align256(size_t x) { return (x + 255) & ~(size_t)255; }

extern "C" void kernel_launch(void* const* d_in, const int* in_sizes, int n_in,
                              void* d_out, int out_size, void* d_ws, size_t ws_size,
                              hipStream_t stream)
{
    const float* x    = (const float*)d_in[0];   // [N, 512]
    const int*   ei   = (const int*)  d_in[1];   // [2, E] int32
    const float* ew   = (const float*)d_in[2];   // [E]
    const float* w    = (const float*)d_in[3];   // [512, 128]
    const float* bias = (const float*)d_in[4];   // [128]
    float*       out  = (float*)d_out;           // [N, 128]

    const int N = in_sizes[0] / F_IN;            // 50000
    const int E = in_sizes[2];                   // 1600000
    const int C = (N + CB - 1) / CB;             // 391 coarse buckets

    // workspace layout (~21.5 MB)
    char*  ws = (char*)d_ws;
    size_t off = 0;
    unsigned short* h      = (unsigned short*)(ws + off); off += align256((size_t)N * F_OUT * 2);
    unsigned short* wt     = (unsigned short*)(ws + off); off += align256((size_t)F_OUT * F_IN * 2);
    int*            cnt    = (int*)(ws + off);            off += align256((size_t)(C + 1) * 4);
    int*            binoff = (int*)(ws + off);            off += align256((size_t)(C + 1) * 4);
    int*            cursor = (int*)(ws + off);            off += align256((size_t)C * 4);
    unsigned*       k32    = (unsigned*)(ws + off);       off += align256((size_t)E * 4);
    unsigned char*  d8     = (unsigned char*)(ws + off);  off += align256((size_t)E);

    const int pblocks = (E + EPB - 1) / EPB;     // 391

    (void)hipMemsetAsync(cnt, 0, (size_t)C * 4, stream);
    coarse_hist<<<pblocks, 512, 0, stream>>>(ei, cnt, E, C);
    scan_convert<<<1 + (F_IN * F_OUT) / 512, 512, 0, stream>>>(cnt, binoff, cursor, C, E, w, wt);
    coarse_fill<<<pblocks, 512, 0, stream>>>(ei, ew, cursor, k32, d8, E, C);
    gemm_mfma<<<(N + 63) / 64, 256, 0, stream>>>(x, wt, h, N);
    fine_agg<<<C, 512, 0, stream>>>(h, k32, d8, binoff, bias, out, N);
}